// Round 1
// baseline (2433.315 us; speedup 1.0000x reference)
//
#include <hip/hip_runtime.h>

// Problem constants (match reference).
#define B_SZ 16384
#define C_SZ 4096
#define D_SZ 512

constexpr int BM = 64;   // rows (x) per block
constexpr int BN = 64;   // cols (codes) per N-tile
constexpr int BK = 32;   // k-depth per stage

// ---------------------------------------------------------------------------
// Kernel A: c_sq[c] = sum_d codes[c][d]^2 ; also zero the loss slot in d_out.
// One wave (64 lanes) per code row; 512 floats = 2 float4 per lane.
// ---------------------------------------------------------------------------
__global__ __launch_bounds__(256) void csq_kernel(const float* __restrict__ codes,
                                                  float* __restrict__ csq,
                                                  float* __restrict__ loss_slot) {
    const int t = threadIdx.x;
    const int wave = t >> 6;
    const int lane = t & 63;
    const int code = blockIdx.x * 4 + wave;

    const float4* cp = (const float4*)(codes + (size_t)code * D_SZ);
    float4 a = cp[lane];
    float4 b = cp[lane + 64];
    float s = a.x * a.x + a.y * a.y + a.z * a.z + a.w * a.w
            + b.x * b.x + b.y * b.y + b.z * b.z + b.w * b.w;
    #pragma unroll
    for (int off = 32; off; off >>= 1) s += __shfl_down(s, off, 64);
    if (lane == 0) csq[code] = s;
    if (blockIdx.x == 0 && t == 0) *loss_slot = 0.0f;
}

// ---------------------------------------------------------------------------
// Kernel B: fused distance GEMM + argmin.
// Block = 256 threads handles BM=64 rows; loops over all C in BN=64 tiles.
// Thread (r = t/16, cg = t%16) owns a 4x4 micro-tile: rows r*4..+3, cols cg*4..+3.
// dist = c_sq[c] - 2*dot(x_b, code_c)   (x_sq dropped: constant per row).
// Running argmin kept in registers of the cg==0 thread of each row-group.
// ---------------------------------------------------------------------------
__global__ __launch_bounds__(256) void argmin_kernel(const float* __restrict__ x,
                                                     const float* __restrict__ codes,
                                                     const float* __restrict__ csq,
                                                     int* __restrict__ out_idx_i,
                                                     float* __restrict__ out_idx_f) {
    // Transposed tiles: [k][row/col], padded +4 to keep 16B alignment and
    // break staging-store bank collisions.
    __shared__ float xs[BK][BM + 4];
    __shared__ float cs[BK][BN + 4];

    const int t = threadIdx.x;
    const int r = t >> 4;    // row-group 0..15
    const int cg = t & 15;   // col-group 0..15
    const int rowbase = blockIdx.x * BM;

    float best_v[4];
    int best_i[4];
    #pragma unroll
    for (int i = 0; i < 4; ++i) { best_v[i] = 3.4e38f; best_i[i] = 0; }

    for (int nt = 0; nt < C_SZ / BN; ++nt) {
        float acc[4][4];
        #pragma unroll
        for (int i = 0; i < 4; ++i)
            #pragma unroll
            for (int j = 0; j < 4; ++j) acc[i][j] = 0.0f;

        for (int kt = 0; kt < D_SZ / BK; ++kt) {
            // Stage x-tile and codes-tile (transposed) into LDS.
            // 64 rows * 8 float4 = 512 float4 each -> 2 per thread.
            for (int i = t; i < (BM * BK) / 4; i += 256) {
                const int row = i >> 3;
                const int kc = i & 7;
                float4 v = *(const float4*)(x + (size_t)(rowbase + row) * D_SZ + kt * BK + kc * 4);
                xs[kc * 4 + 0][row] = v.x;
                xs[kc * 4 + 1][row] = v.y;
                xs[kc * 4 + 2][row] = v.z;
                xs[kc * 4 + 3][row] = v.w;
                float4 w = *(const float4*)(codes + (size_t)(nt * BN + row) * D_SZ + kt * BK + kc * 4);
                cs[kc * 4 + 0][row] = w.x;
                cs[kc * 4 + 1][row] = w.y;
                cs[kc * 4 + 2][row] = w.z;
                cs[kc * 4 + 3][row] = w.w;
            }
            __syncthreads();

            #pragma unroll
            for (int k = 0; k < BK; ++k) {
                float4 a = *(const float4*)&xs[k][r * 4];
                float4 b = *(const float4*)&cs[k][cg * 4];
                const float av[4] = {a.x, a.y, a.z, a.w};
                const float bv[4] = {b.x, b.y, b.z, b.w};
                #pragma unroll
                for (int i = 0; i < 4; ++i)
                    #pragma unroll
                    for (int j = 0; j < 4; ++j)
                        acc[i][j] = fmaf(av[i], bv[j], acc[i][j]);
            }
            __syncthreads();
        }

        // Argmin update for this 64-col tile.
        #pragma unroll
        for (int i = 0; i < 4; ++i) {
            float v = 3.4e38f;
            int idx = 0;
            #pragma unroll
            for (int j = 0; j < 4; ++j) {
                const int col = nt * BN + cg * 4 + j;
                const float d = csq[col] - 2.0f * acc[i][j];
                if (d < v) { v = d; idx = col; }   // first-wins on ties (j asc)
            }
            // Min-reduce (value, index) across the 16 lanes of this row-group.
            #pragma unroll
            for (int off = 8; off; off >>= 1) {
                const float ov = __shfl_down(v, off, 16);
                const int oi = __shfl_down(idx, off, 16);
                if (ov < v || (ov == v && oi < idx)) { v = ov; idx = oi; }
            }
            if (cg == 0) {
                if (v < best_v[i] || (v == best_v[i] && idx < best_i[i])) {
                    best_v[i] = v;
                    best_i[i] = idx;
                }
            }
        }
    }

    if (cg == 0) {
        #pragma unroll
        for (int i = 0; i < 4; ++i) {
            const int row = rowbase + r * 4 + i;
            out_idx_i[row] = best_i[i];
            out_idx_f[row] = (float)best_i[i];
        }
    }
}

// ---------------------------------------------------------------------------
// Kernel C: quantized = codes[idx] gather + loss = 1.25 * mean(sum((x-q)^2)).
// One wave per row; 2 float4 per lane; wave shuffle-reduce; 1 atomic per row.
// ---------------------------------------------------------------------------
__global__ __launch_bounds__(256) void gather_loss_kernel(const float* __restrict__ x,
                                                          const float* __restrict__ codes,
                                                          const int* __restrict__ idx,
                                                          float* __restrict__ outq,
                                                          float* __restrict__ loss_slot) {
    const int t = threadIdx.x;
    const int wave = t >> 6;
    const int lane = t & 63;
    const int row = blockIdx.x * 4 + wave;

    const int ci = idx[row];
    const float4* cp = (const float4*)(codes + (size_t)ci * D_SZ);
    const float4* xp = (const float4*)(x + (size_t)row * D_SZ);
    float4* op = (float4*)(outq + (size_t)row * D_SZ);

    float s = 0.0f;
    #pragma unroll
    for (int u = 0; u < 2; ++u) {
        const float4 q = cp[lane + 64 * u];
        const float4 xv = xp[lane + 64 * u];
        op[lane + 64 * u] = q;
        const float dx = xv.x - q.x;
        const float dy = xv.y - q.y;
        const float dz = xv.z - q.z;
        const float dw = xv.w - q.w;
        s += dx * dx + dy * dy + dz * dz + dw * dw;
    }
    #pragma unroll
    for (int off = 32; off; off >>= 1) s += __shfl_down(s, off, 64);
    if (lane == 0) atomicAdd(loss_slot, s * (1.25f / (float)B_SZ));
}

// ---------------------------------------------------------------------------
extern "C" void kernel_launch(void* const* d_in, const int* in_sizes, int n_in,
                              void* d_out, int out_size, void* d_ws, size_t ws_size,
                              hipStream_t stream) {
    const float* x = (const float*)d_in[0];
    const float* codes = (const float*)d_in[1];  // (1, C, D) contiguous

    float* outq = (float*)d_out;                          // [B*D]
    float* out_idx_f = outq + (size_t)B_SZ * D_SZ;        // [B] indices as float
    float* loss_slot = out_idx_f + B_SZ;                  // [1]

    float* csq = (float*)d_ws;                                     // [C]
    int* idx = (int*)((char*)d_ws + C_SZ * sizeof(float));         // [B]

    csq_kernel<<<C_SZ / 4, 256, 0, stream>>>(codes, csq, loss_slot);
    argmin_kernel<<<B_SZ / BM, 256, 0, stream>>>(x, codes, csq, idx, out_idx_f);
    gather_loss_kernel<<<B_SZ / 4, 256, 0, stream>>>(x, codes, idx, outq, loss_slot);
}

// Round 2
// 562.831 us; speedup vs baseline: 4.3234x; 4.3234x over previous
//
#include <hip/hip_runtime.h>

// Problem constants.
#define B_SZ 16384
#define C_SZ 4096
#define D_SZ 512

typedef __attribute__((ext_vector_type(8))) short short8;   // 8 bf16 = 4 VGPRs
typedef __attribute__((ext_vector_type(4))) float floatx4;  // MFMA acc

// ---- helpers ---------------------------------------------------------------
__device__ inline unsigned short f2bf(float f) {
    unsigned u = __float_as_uint(f);
    unsigned r = u + 0x7FFFu + ((u >> 16) & 1u);   // round-to-nearest-even
    return (unsigned short)(r >> 16);
}
__device__ inline float bf2f(unsigned short h) {
    return __uint_as_float((unsigned)h << 16);
}
__device__ inline void gload16(const void* g, void* l) {
    // async global->LDS, 16B/lane; LDS dest = wave-uniform base + lane*16
    __builtin_amdgcn_global_load_lds(
        (const __attribute__((address_space(1))) void*)g,
        (__attribute__((address_space(3))) void*)l, 16, 0, 0);
}

// ---------------------------------------------------------------------------
// Prep 1: x (B x D fp32) -> bf16 hi/lo planes. Also init argmin keys + loss.
// ---------------------------------------------------------------------------
__global__ __launch_bounds__(256) void convert_x_kernel(const float* __restrict__ x,
                                                        unsigned short* __restrict__ xhi,
                                                        unsigned short* __restrict__ xlo,
                                                        unsigned long long* __restrict__ keys,
                                                        float* __restrict__ loss_slot) {
    const int tid = blockIdx.x * 256 + threadIdx.x;
    const float4 v = ((const float4*)x)[tid];
    const float f[4] = {v.x, v.y, v.z, v.w};
    unsigned short h[4], l[4];
    #pragma unroll
    for (int i = 0; i < 4; ++i) {
        h[i] = f2bf(f[i]);
        l[i] = f2bf(f[i] - bf2f(h[i]));
    }
    ((ushort4*)xhi)[tid] = make_ushort4(h[0], h[1], h[2], h[3]);
    ((ushort4*)xlo)[tid] = make_ushort4(l[0], l[1], l[2], l[3]);

    if (blockIdx.x < B_SZ / 256) keys[tid] = ~0ull;
    if (tid == 0) *loss_slot = 0.0f;
}

// ---------------------------------------------------------------------------
// Prep 2: codes -> bf16 hi/lo planes.
// ---------------------------------------------------------------------------
__global__ __launch_bounds__(256) void convert_c_kernel(const float* __restrict__ codes,
                                                        unsigned short* __restrict__ chi,
                                                        unsigned short* __restrict__ clo) {
    const int tid = blockIdx.x * 256 + threadIdx.x;
    const float4 v = ((const float4*)codes)[tid];
    const float f[4] = {v.x, v.y, v.z, v.w};
    unsigned short h[4], l[4];
    #pragma unroll
    for (int i = 0; i < 4; ++i) {
        h[i] = f2bf(f[i]);
        l[i] = f2bf(f[i] - bf2f(h[i]));
    }
    ((ushort4*)chi)[tid] = make_ushort4(h[0], h[1], h[2], h[3]);
    ((ushort4*)clo)[tid] = make_ushort4(l[0], l[1], l[2], l[3]);
}

// ---------------------------------------------------------------------------
// Prep 3: c_sq[c] = sum_d codes[c][d]^2 (fp32, one wave per code).
// ---------------------------------------------------------------------------
__global__ __launch_bounds__(256) void csq_kernel(const float* __restrict__ codes,
                                                  float* __restrict__ csq) {
    const int t = threadIdx.x;
    const int wave = t >> 6;
    const int lane = t & 63;
    const int code = blockIdx.x * 4 + wave;
    const float4* cp = (const float4*)(codes + (size_t)code * D_SZ);
    float4 a = cp[lane];
    float4 b = cp[lane + 64];
    float s = a.x * a.x + a.y * a.y + a.z * a.z + a.w * a.w
            + b.x * b.x + b.y * b.y + b.z * b.z + b.w * b.w;
    #pragma unroll
    for (int off = 32; off; off >>= 1) s += __shfl_down(s, off, 64);
    if (lane == 0) csq[code] = s;
}

// ---------------------------------------------------------------------------
// Main: split-bf16 MFMA GEMM (dot = hi*hi + hi*lo + lo*hi) + fused argmin.
// 128x128 tile, BK=32, 4 waves; wave w: rows (w>>1)*64, cols (w&1)*64, 4x4
// 16x16 MFMA tiles. Staging: wave s stages one of {Ahi,Alo,Bhi,Blo} via
// global_load_lds width 16. Epilogue: dist = 0.5*csq - dot, 16-lane shuffle
// argmin, atomicMin on packed (ordered-float<<32 | col) key -> lowest-index
// tie-break for free.
// ---------------------------------------------------------------------------
__global__ __launch_bounds__(256) void gemm_argmin_kernel(
        const unsigned short* __restrict__ xhi, const unsigned short* __restrict__ xlo,
        const unsigned short* __restrict__ chi, const unsigned short* __restrict__ clo,
        const float* __restrict__ csq,
        unsigned long long* __restrict__ keys) {
    __shared__ unsigned short sAhi[128][32];
    __shared__ unsigned short sAlo[128][32];
    __shared__ unsigned short sBhi[128][32];
    __shared__ unsigned short sBlo[128][32];

    const int t = threadIdx.x;
    const int wave = t >> 6;
    const int lane = t & 63;
    const int quad = lane >> 4;
    const int l15 = lane & 15;

    const int rowbase = blockIdx.y * 128;   // x rows
    const int colbase = blockIdx.x * 128;   // code cols
    const int wr = (wave >> 1) * 64;
    const int wc = (wave & 1) * 64;

    // staging assignment (per wave)
    const unsigned short* gsrc;
    unsigned short(*ltile)[32];
    if (wave == 0)      { gsrc = xhi + (size_t)rowbase * D_SZ; ltile = sAhi; }
    else if (wave == 1) { gsrc = xlo + (size_t)rowbase * D_SZ; ltile = sAlo; }
    else if (wave == 2) { gsrc = chi + (size_t)colbase * D_SZ; ltile = sBhi; }
    else                { gsrc = clo + (size_t)colbase * D_SZ; ltile = sBlo; }
    const unsigned short* gbase = gsrc + (size_t)((lane >> 2) * D_SZ) + (lane & 3) * 8;

    floatx4 acc[4][4];
    #pragma unroll
    for (int i = 0; i < 4; ++i)
        #pragma unroll
        for (int j = 0; j < 4; ++j) acc[i][j] = (floatx4)0.0f;

    for (int kt = 0; kt < D_SZ / 32; ++kt) {
        // ---- stage this wave's tile: 8 x 16B/lane -> 128 rows x 32 bf16
        const unsigned short* g = gbase + kt * 32;
        #pragma unroll
        for (int inst = 0; inst < 8; ++inst)
            gload16(g + (size_t)(inst * 16) * D_SZ, &ltile[inst * 16][0]);
        __syncthreads();

        // ---- fragments (A[m=l15][k=quad*8+j], B[n=l15][k=quad*8+j])
        short8 ahi[4], alo[4], bhi[4], blo[4];
        #pragma unroll
        for (int i = 0; i < 4; ++i) {
            ahi[i] = *(const short8*)&sAhi[wr + i * 16 + l15][quad * 8];
            alo[i] = *(const short8*)&sAlo[wr + i * 16 + l15][quad * 8];
            bhi[i] = *(const short8*)&sBhi[wc + i * 16 + l15][quad * 8];
            blo[i] = *(const short8*)&sBlo[wc + i * 16 + l15][quad * 8];
        }
        #pragma unroll
        for (int i = 0; i < 4; ++i)
            #pragma unroll
            for (int j = 0; j < 4; ++j) {
                acc[i][j] = __builtin_amdgcn_mfma_f32_16x16x32_bf16(ahi[i], bhi[j], acc[i][j], 0, 0, 0);
                acc[i][j] = __builtin_amdgcn_mfma_f32_16x16x32_bf16(ahi[i], blo[j], acc[i][j], 0, 0, 0);
                acc[i][j] = __builtin_amdgcn_mfma_f32_16x16x32_bf16(alo[i], bhi[j], acc[i][j], 0, 0, 0);
            }
        __syncthreads();
    }

    // ---- epilogue: dist = 0.5*csq - dot (order-equivalent to csq - 2*dot)
    float cs[4];
    #pragma unroll
    for (int j = 0; j < 4; ++j)
        cs[j] = 0.5f * csq[colbase + wc + j * 16 + l15];

    #pragma unroll
    for (int i = 0; i < 4; ++i) {
        #pragma unroll
        for (int r = 0; r < 4; ++r) {
            float best = 3.4e38f;
            int bidx = 0;
            #pragma unroll
            for (int j = 0; j < 4; ++j) {
                const float d = cs[j] - acc[i][j][r];
                const int col = colbase + wc + j * 16 + l15;
                if (d < best) { best = d; bidx = col; }  // lowest col wins ties
            }
            #pragma unroll
            for (int off = 8; off; off >>= 1) {
                const float ov = __shfl_down(best, off, 16);
                const int oi = __shfl_down(bidx, off, 16);
                if (ov < best || (ov == best && oi < bidx)) { best = ov; bidx = oi; }
            }
            if (l15 == 0) {
                const unsigned u = __float_as_uint(best);
                const unsigned key32 = (u & 0x80000000u) ? ~u : (u | 0x80000000u);
                const unsigned long long key = ((unsigned long long)key32 << 32) | (unsigned)bidx;
                atomicMin(&keys[rowbase + wr + i * 16 + quad * 4 + r], key);
            }
        }
    }
}

// ---------------------------------------------------------------------------
// Final: idx from key; quantized = codes[idx]; loss = 1.25*mean(sum((x-q)^2)).
// ---------------------------------------------------------------------------
__global__ __launch_bounds__(256) void gather_loss_kernel(const float* __restrict__ x,
                                                          const float* __restrict__ codes,
                                                          const unsigned long long* __restrict__ keys,
                                                          float* __restrict__ outq,
                                                          float* __restrict__ out_idx_f,
                                                          float* __restrict__ loss_slot) {
    const int t = threadIdx.x;
    const int wave = t >> 6;
    const int lane = t & 63;
    const int row = blockIdx.x * 4 + wave;

    const int ci = (int)(keys[row] & 0xFFFFFFFFull);
    const float4* cp = (const float4*)(codes + (size_t)ci * D_SZ);
    const float4* xp = (const float4*)(x + (size_t)row * D_SZ);
    float4* op = (float4*)(outq + (size_t)row * D_SZ);

    float s = 0.0f;
    #pragma unroll
    for (int u = 0; u < 2; ++u) {
        const float4 q = cp[lane + 64 * u];
        const float4 xv = xp[lane + 64 * u];
        op[lane + 64 * u] = q;
        const float dx = xv.x - q.x;
        const float dy = xv.y - q.y;
        const float dz = xv.z - q.z;
        const float dw = xv.w - q.w;
        s += dx * dx + dy * dy + dz * dz + dw * dw;
    }
    #pragma unroll
    for (int off = 32; off; off >>= 1) s += __shfl_down(s, off, 64);
    if (lane == 0) {
        atomicAdd(loss_slot, s * (1.25f / (float)B_SZ));
        out_idx_f[row] = (float)ci;
    }
}

// ---------------------------------------------------------------------------
extern "C" void kernel_launch(void* const* d_in, const int* in_sizes, int n_in,
                              void* d_out, int out_size, void* d_ws, size_t ws_size,
                              hipStream_t stream) {
    const float* x = (const float*)d_in[0];
    const float* codes = (const float*)d_in[1];  // (1, C, D) contiguous

    float* outq = (float*)d_out;                       // [B*D]
    float* out_idx_f = outq + (size_t)B_SZ * D_SZ;     // [B]
    float* loss_slot = out_idx_f + B_SZ;               // [1]

    // workspace layout (bytes): xhi 16M | xlo 16M | chi 4M | clo 4M | csq 16K | keys 128K
    unsigned short* xhi = (unsigned short*)d_ws;
    unsigned short* xlo = xhi + (size_t)B_SZ * D_SZ;
    unsigned short* chi = xlo + (size_t)B_SZ * D_SZ;
    unsigned short* clo = chi + (size_t)C_SZ * D_SZ;
    float* csq = (float*)(clo + (size_t)C_SZ * D_SZ);
    unsigned long long* keys = (unsigned long long*)(csq + C_SZ);

    convert_x_kernel<<<(B_SZ * D_SZ) / 4 / 256, 256, 0, stream>>>(x, xhi, xlo, keys, loss_slot);
    convert_c_kernel<<<(C_SZ * D_SZ) / 4 / 256, 256, 0, stream>>>(codes, chi, clo);
    csq_kernel<<<C_SZ / 4, 256, 0, stream>>>(codes, csq);
    gemm_argmin_kernel<<<dim3(C_SZ / 128, B_SZ / 128), 256, 0, stream>>>(xhi, xlo, chi, clo, csq, keys);
    gather_loss_kernel<<<B_SZ / 4, 256, 0, stream>>>(x, codes, keys, outq, out_idx_f, loss_slot);
}

// Round 3
// 356.091 us; speedup vs baseline: 6.8334x; 1.5806x over previous
//
#include <hip/hip_runtime.h>

// Problem constants.
#define B_SZ 16384
#define C_SZ 4096
#define D_SZ 512

typedef __attribute__((ext_vector_type(8))) short short8;   // 8 bf16 = 4 VGPRs
typedef __attribute__((ext_vector_type(4))) float floatx4;  // MFMA acc

// ---- helpers ---------------------------------------------------------------
__device__ inline unsigned short f2bf(float f) {
    unsigned u = __float_as_uint(f);
    unsigned r = u + 0x7FFFu + ((u >> 16) & 1u);   // round-to-nearest-even
    return (unsigned short)(r >> 16);
}
__device__ inline float bf2f(unsigned short h) {
    return __uint_as_float((unsigned)h << 16);
}
__device__ inline void gload16(const void* g, void* l) {
    // async global->LDS, 16B/lane; LDS dest = wave-uniform base + lane*16
    __builtin_amdgcn_global_load_lds(
        (const __attribute__((address_space(1))) void*)g,
        (__attribute__((address_space(3))) void*)l, 16, 0, 0);
}

// ---------------------------------------------------------------------------
// Prep 1: x (B x D fp32) -> bf16 hi/lo planes. Also init argmin keys.
// ---------------------------------------------------------------------------
__global__ __launch_bounds__(256) void convert_x_kernel(const float* __restrict__ x,
                                                        unsigned short* __restrict__ xhi,
                                                        unsigned short* __restrict__ xlo,
                                                        unsigned long long* __restrict__ keys) {
    const int tid = blockIdx.x * 256 + threadIdx.x;
    const float4 v = ((const float4*)x)[tid];
    const float f[4] = {v.x, v.y, v.z, v.w};
    unsigned short h[4], l[4];
    #pragma unroll
    for (int i = 0; i < 4; ++i) {
        h[i] = f2bf(f[i]);
        l[i] = f2bf(f[i] - bf2f(h[i]));
    }
    ((ushort4*)xhi)[tid] = make_ushort4(h[0], h[1], h[2], h[3]);
    ((ushort4*)xlo)[tid] = make_ushort4(l[0], l[1], l[2], l[3]);

    if (blockIdx.x < B_SZ / 256) keys[tid] = ~0ull;
}

// ---------------------------------------------------------------------------
// Prep 2 (merged): codes -> bf16 hi/lo planes AND c_sq[c] = sum_d codes^2.
// One wave per code row: 512 floats = 2 float4 per lane.
// ---------------------------------------------------------------------------
__global__ __launch_bounds__(256) void convert_c_csq_kernel(const float* __restrict__ codes,
                                                            unsigned short* __restrict__ chi,
                                                            unsigned short* __restrict__ clo,
                                                            float* __restrict__ csq) {
    const int t = threadIdx.x;
    const int wave = t >> 6;
    const int lane = t & 63;
    const int code = blockIdx.x * 4 + wave;

    const float4* cp = (const float4*)(codes + (size_t)code * D_SZ);
    float s = 0.0f;
    #pragma unroll
    for (int u = 0; u < 2; ++u) {
        const float4 v = cp[lane + 64 * u];
        const float f[4] = {v.x, v.y, v.z, v.w};
        unsigned short h[4], l[4];
        #pragma unroll
        for (int i = 0; i < 4; ++i) {
            h[i] = f2bf(f[i]);
            l[i] = f2bf(f[i] - bf2f(h[i]));
            s = fmaf(f[i], f[i], s);
        }
        ((ushort4*)chi)[(size_t)code * (D_SZ / 4) + lane + 64 * u] = make_ushort4(h[0], h[1], h[2], h[3]);
        ((ushort4*)clo)[(size_t)code * (D_SZ / 4) + lane + 64 * u] = make_ushort4(l[0], l[1], l[2], l[3]);
    }
    #pragma unroll
    for (int off = 32; off; off >>= 1) s += __shfl_down(s, off, 64);
    if (lane == 0) csq[code] = s;
}

// ---------------------------------------------------------------------------
// Main: split-bf16 MFMA GEMM (dot = hi*hi + hi*lo + lo*hi) + fused argmin.
// (unchanged from R2 — isolating the loss-reduction fix this round)
// ---------------------------------------------------------------------------
__global__ __launch_bounds__(256) void gemm_argmin_kernel(
        const unsigned short* __restrict__ xhi, const unsigned short* __restrict__ xlo,
        const unsigned short* __restrict__ chi, const unsigned short* __restrict__ clo,
        const float* __restrict__ csq,
        unsigned long long* __restrict__ keys) {
    __shared__ unsigned short sAhi[128][32];
    __shared__ unsigned short sAlo[128][32];
    __shared__ unsigned short sBhi[128][32];
    __shared__ unsigned short sBlo[128][32];

    const int t = threadIdx.x;
    const int wave = t >> 6;
    const int lane = t & 63;
    const int quad = lane >> 4;
    const int l15 = lane & 15;

    const int rowbase = blockIdx.y * 128;   // x rows
    const int colbase = blockIdx.x * 128;   // code cols
    const int wr = (wave >> 1) * 64;
    const int wc = (wave & 1) * 64;

    // staging assignment (per wave)
    const unsigned short* gsrc;
    unsigned short(*ltile)[32];
    if (wave == 0)      { gsrc = xhi + (size_t)rowbase * D_SZ; ltile = sAhi; }
    else if (wave == 1) { gsrc = xlo + (size_t)rowbase * D_SZ; ltile = sAlo; }
    else if (wave == 2) { gsrc = chi + (size_t)colbase * D_SZ; ltile = sBhi; }
    else                { gsrc = clo + (size_t)colbase * D_SZ; ltile = sBlo; }
    const unsigned short* gbase = gsrc + (size_t)((lane >> 2) * D_SZ) + (lane & 3) * 8;

    floatx4 acc[4][4];
    #pragma unroll
    for (int i = 0; i < 4; ++i)
        #pragma unroll
        for (int j = 0; j < 4; ++j) acc[i][j] = (floatx4)0.0f;

    for (int kt = 0; kt < D_SZ / 32; ++kt) {
        // ---- stage this wave's tile: 8 x 16B/lane -> 128 rows x 32 bf16
        const unsigned short* g = gbase + kt * 32;
        #pragma unroll
        for (int inst = 0; inst < 8; ++inst)
            gload16(g + (size_t)(inst * 16) * D_SZ, &ltile[inst * 16][0]);
        __syncthreads();

        // ---- fragments (A[m=l15][k=quad*8+j], B[n=l15][k=quad*8+j])
        short8 ahi[4], alo[4], bhi[4], blo[4];
        #pragma unroll
        for (int i = 0; i < 4; ++i) {
            ahi[i] = *(const short8*)&sAhi[wr + i * 16 + l15][quad * 8];
            alo[i] = *(const short8*)&sAlo[wr + i * 16 + l15][quad * 8];
            bhi[i] = *(const short8*)&sBhi[wc + i * 16 + l15][quad * 8];
            blo[i] = *(const short8*)&sBlo[wc + i * 16 + l15][quad * 8];
        }
        #pragma unroll
        for (int i = 0; i < 4; ++i)
            #pragma unroll
            for (int j = 0; j < 4; ++j) {
                acc[i][j] = __builtin_amdgcn_mfma_f32_16x16x32_bf16(ahi[i], bhi[j], acc[i][j], 0, 0, 0);
                acc[i][j] = __builtin_amdgcn_mfma_f32_16x16x32_bf16(ahi[i], blo[j], acc[i][j], 0, 0, 0);
                acc[i][j] = __builtin_amdgcn_mfma_f32_16x16x32_bf16(alo[i], bhi[j], acc[i][j], 0, 0, 0);
            }
        __syncthreads();
    }

    // ---- epilogue: dist = 0.5*csq - dot (order-equivalent to csq - 2*dot)
    float cs[4];
    #pragma unroll
    for (int j = 0; j < 4; ++j)
        cs[j] = 0.5f * csq[colbase + wc + j * 16 + l15];

    #pragma unroll
    for (int i = 0; i < 4; ++i) {
        #pragma unroll
        for (int r = 0; r < 4; ++r) {
            float best = 3.4e38f;
            int bidx = 0;
            #pragma unroll
            for (int j = 0; j < 4; ++j) {
                const float d = cs[j] - acc[i][j][r];
                const int col = colbase + wc + j * 16 + l15;
                if (d < best) { best = d; bidx = col; }  // lowest col wins ties
            }
            #pragma unroll
            for (int off = 8; off; off >>= 1) {
                const float ov = __shfl_down(best, off, 16);
                const int oi = __shfl_down(bidx, off, 16);
                if (ov < best || (ov == best && oi < bidx)) { best = ov; bidx = oi; }
            }
            if (l15 == 0) {
                const unsigned u = __float_as_uint(best);
                const unsigned key32 = (u & 0x80000000u) ? ~u : (u | 0x80000000u);
                const unsigned long long key = ((unsigned long long)key32 << 32) | (unsigned)bidx;
                atomicMin(&keys[rowbase + wr + i * 16 + quad * 4 + r], key);
            }
        }
    }
}

// ---------------------------------------------------------------------------
// Final: idx from key; quantized = codes[idx]; per-block loss partial to ws
// (NO single-address atomics — that cost ~250 us in R2).
// ---------------------------------------------------------------------------
__global__ __launch_bounds__(256) void gather_loss_kernel(const float* __restrict__ x,
                                                          const float* __restrict__ codes,
                                                          const unsigned long long* __restrict__ keys,
                                                          float* __restrict__ outq,
                                                          float* __restrict__ out_idx_f,
                                                          float* __restrict__ partials) {
    __shared__ float red[4];
    const int t = threadIdx.x;
    const int wave = t >> 6;
    const int lane = t & 63;
    const int row = blockIdx.x * 4 + wave;

    const int ci = (int)(keys[row] & 0xFFFFFFFFull);
    const float4* cp = (const float4*)(codes + (size_t)ci * D_SZ);
    const float4* xp = (const float4*)(x + (size_t)row * D_SZ);
    float4* op = (float4*)(outq + (size_t)row * D_SZ);

    float s = 0.0f;
    #pragma unroll
    for (int u = 0; u < 2; ++u) {
        const float4 q = cp[lane + 64 * u];
        const float4 xv = xp[lane + 64 * u];
        op[lane + 64 * u] = q;
        const float dx = xv.x - q.x;
        const float dy = xv.y - q.y;
        const float dz = xv.z - q.z;
        const float dw = xv.w - q.w;
        s += dx * dx + dy * dy + dz * dz + dw * dw;
    }
    #pragma unroll
    for (int off = 32; off; off >>= 1) s += __shfl_down(s, off, 64);
    if (lane == 0) {
        red[wave] = s;
        out_idx_f[row] = (float)ci;
    }
    __syncthreads();
    if (t == 0) partials[blockIdx.x] = red[0] + red[1] + red[2] + red[3];
}

// ---------------------------------------------------------------------------
// Loss: sum 4096 block partials -> loss_slot. One block.
// ---------------------------------------------------------------------------
__global__ __launch_bounds__(256) void loss_reduce_kernel(const float* __restrict__ partials,
                                                          float* __restrict__ loss_slot) {
    __shared__ float red[4];
    const int t = threadIdx.x;
    const int wave = t >> 6;
    const int lane = t & 63;
    float s = 0.0f;
    #pragma unroll
    for (int i = 0; i < (B_SZ / 4) / 256; ++i) s += partials[i * 256 + t];
    #pragma unroll
    for (int off = 32; off; off >>= 1) s += __shfl_down(s, off, 64);
    if (lane == 0) red[wave] = s;
    __syncthreads();
    if (t == 0)
        *loss_slot = (red[0] + red[1] + red[2] + red[3]) * (1.25f / (float)B_SZ);
}

// ---------------------------------------------------------------------------
extern "C" void kernel_launch(void* const* d_in, const int* in_sizes, int n_in,
                              void* d_out, int out_size, void* d_ws, size_t ws_size,
                              hipStream_t stream) {
    const float* x = (const float*)d_in[0];
    const float* codes = (const float*)d_in[1];  // (1, C, D) contiguous

    float* outq = (float*)d_out;                       // [B*D]
    float* out_idx_f = outq + (size_t)B_SZ * D_SZ;     // [B]
    float* loss_slot = out_idx_f + B_SZ;               // [1]

    // workspace: xhi 16M | xlo 16M | chi 4M | clo 4M | csq 16K | keys 128K | partials 16K
    unsigned short* xhi = (unsigned short*)d_ws;
    unsigned short* xlo = xhi + (size_t)B_SZ * D_SZ;
    unsigned short* chi = xlo + (size_t)B_SZ * D_SZ;
    unsigned short* clo = chi + (size_t)C_SZ * D_SZ;
    float* csq = (float*)(clo + (size_t)C_SZ * D_SZ);
    unsigned long long* keys = (unsigned long long*)(csq + C_SZ);
    float* partials = (float*)(keys + B_SZ);

    convert_x_kernel<<<(B_SZ * D_SZ) / 4 / 256, 256, 0, stream>>>(x, xhi, xlo, keys);
    convert_c_csq_kernel<<<C_SZ / 4, 256, 0, stream>>>(codes, chi, clo, csq);
    gemm_argmin_kernel<<<dim3(C_SZ / 128, B_SZ / 128), 256, 0, stream>>>(xhi, xlo, chi, clo, csq, keys);
    gather_loss_kernel<<<B_SZ / 4, 256, 0, stream>>>(x, codes, keys, outq, out_idx_f, partials);
    loss_reduce_kernel<<<1, 256, 0, stream>>>(partials, loss_slot);
}

// Round 4
// 241.772 us; speedup vs baseline: 10.0645x; 1.4728x over previous
//
#include <hip/hip_runtime.h>

// Problem constants.
#define B_SZ 16384
#define C_SZ 4096
#define D_SZ 512

// Re-rank threshold in "dist units" (raw_l2/2). bf16 hi*hi dot error sigma
// ~= 0.07 in these units (CLT over K=512, rel err 2^-8/op); 1.0 = ~14 sigma.
#define EPS 1.0f

typedef __attribute__((ext_vector_type(8))) short short8;   // 8 bf16 = 4 VGPRs
typedef __attribute__((ext_vector_type(4))) float floatx4;  // MFMA acc

// ---- helpers ---------------------------------------------------------------
__device__ inline unsigned short f2bf(float f) {
    unsigned u = __float_as_uint(f);
    unsigned r = u + 0x7FFFu + ((u >> 16) & 1u);   // round-to-nearest-even
    return (unsigned short)(r >> 16);
}
__device__ inline void gload16(const void* g, void* l) {
    // async global->LDS, 16B/lane; LDS dest = wave-uniform base + lane*16
    __builtin_amdgcn_global_load_lds(
        (const __attribute__((address_space(1))) void*)g,
        (__attribute__((address_space(3))) void*)l, 16, 0, 0);
}

// ---------------------------------------------------------------------------
// Prep 1: x (B x D fp32) -> bf16 hi plane only.
// ---------------------------------------------------------------------------
__global__ __launch_bounds__(256) void convert_x_kernel(const float* __restrict__ x,
                                                        unsigned short* __restrict__ xhi) {
    const int tid = blockIdx.x * 256 + threadIdx.x;
    const float4 v = ((const float4*)x)[tid];
    ((ushort4*)xhi)[tid] = make_ushort4(f2bf(v.x), f2bf(v.y), f2bf(v.z), f2bf(v.w));
}

// ---------------------------------------------------------------------------
// Prep 2: codes -> bf16 hi plane AND c_sq[c] (fp32). One wave per code row.
// ---------------------------------------------------------------------------
__global__ __launch_bounds__(256) void convert_c_csq_kernel(const float* __restrict__ codes,
                                                            unsigned short* __restrict__ chi,
                                                            float* __restrict__ csq) {
    const int t = threadIdx.x;
    const int wave = t >> 6;
    const int lane = t & 63;
    const int code = blockIdx.x * 4 + wave;

    const float4* cp = (const float4*)(codes + (size_t)code * D_SZ);
    float s = 0.0f;
    #pragma unroll
    for (int u = 0; u < 2; ++u) {
        const float4 v = cp[lane + 64 * u];
        ((ushort4*)chi)[(size_t)code * (D_SZ / 4) + lane + 64 * u] =
            make_ushort4(f2bf(v.x), f2bf(v.y), f2bf(v.z), f2bf(v.w));
        s = fmaf(v.x, v.x, s); s = fmaf(v.y, v.y, s);
        s = fmaf(v.z, v.z, s); s = fmaf(v.w, v.w, s);
    }
    #pragma unroll
    for (int off = 32; off; off >>= 1) s += __shfl_down(s, off, 64);
    if (lane == 0) csq[code] = s;
}

// ---------------------------------------------------------------------------
// Main: hi*hi bf16 MFMA GEMM + fused per-(row, 64-col-half) TOP-2 table.
// 128x128 tile, BK=32, 4 waves. Wave w: rows (w>>1)*64, cols (w&1)*64.
// Staging: waves 0,1 stage A halves; 2,3 stage B halves (4 x gload16 each).
// Epilogue: dist = 0.5*csq - dot; per-lane top2 over 4 cols, 16-lane shuffle
// top2-merge; lane 0 stores float4(v1, i1, v2, i2) -- written exactly once,
// NO atomics.
// ---------------------------------------------------------------------------
__global__ __launch_bounds__(256) void gemm_argmin_kernel(
        const unsigned short* __restrict__ xhi,
        const unsigned short* __restrict__ chi,
        const float* __restrict__ csq,
        float4* __restrict__ table) {
    __shared__ unsigned short sA[128][32];
    __shared__ unsigned short sB[128][32];

    const int t = threadIdx.x;
    const int wave = t >> 6;
    const int lane = t & 63;
    const int quad = lane >> 4;
    const int l15 = lane & 15;

    const int rowbase = blockIdx.y * 128;   // x rows
    const int colbase = blockIdx.x * 128;   // code cols
    const int wr = (wave >> 1) * 64;
    const int wc = (wave & 1) * 64;

    // staging assignment: wave -> 64 rows of one tile
    const unsigned short* gsrc;
    unsigned short(*ltile)[32];
    int rowoff;
    if (wave == 0)      { gsrc = xhi + (size_t)rowbase * D_SZ; ltile = sA; rowoff = 0; }
    else if (wave == 1) { gsrc = xhi + (size_t)rowbase * D_SZ; ltile = sA; rowoff = 64; }
    else if (wave == 2) { gsrc = chi + (size_t)colbase * D_SZ; ltile = sB; rowoff = 0; }
    else                { gsrc = chi + (size_t)colbase * D_SZ; ltile = sB; rowoff = 64; }
    const unsigned short* gbase = gsrc + (size_t)(rowoff + (lane >> 2)) * D_SZ + (lane & 3) * 8;

    floatx4 acc[4][4];
    #pragma unroll
    for (int i = 0; i < 4; ++i)
        #pragma unroll
        for (int j = 0; j < 4; ++j) acc[i][j] = (floatx4)0.0f;

    for (int kt = 0; kt < D_SZ / 32; ++kt) {
        const unsigned short* g = gbase + kt * 32;
        #pragma unroll
        for (int inst = 0; inst < 4; ++inst)
            gload16(g + (size_t)(inst * 16) * D_SZ, &ltile[rowoff + inst * 16][0]);
        __syncthreads();

        short8 a[4], b[4];
        #pragma unroll
        for (int i = 0; i < 4; ++i) {
            a[i] = *(const short8*)&sA[wr + i * 16 + l15][quad * 8];
            b[i] = *(const short8*)&sB[wc + i * 16 + l15][quad * 8];
        }
        #pragma unroll
        for (int i = 0; i < 4; ++i)
            #pragma unroll
            for (int j = 0; j < 4; ++j)
                acc[i][j] = __builtin_amdgcn_mfma_f32_16x16x32_bf16(a[i], b[j], acc[i][j], 0, 0, 0);
        __syncthreads();
    }

    // ---- epilogue: top-2 per (row, this wave's 64 cols)
    float cs[4];
    #pragma unroll
    for (int j = 0; j < 4; ++j)
        cs[j] = 0.5f * csq[colbase + wc + j * 16 + l15];

    const int hb = blockIdx.x * 2 + (wave & 1);   // 64-col half index, 0..63

    #pragma unroll
    for (int i = 0; i < 4; ++i) {
        #pragma unroll
        for (int r = 0; r < 4; ++r) {
            float v1 = 3.4e38f, v2 = 3.4e38f;
            int i1 = 0x7FFFFFFF, i2 = 0x7FFFFFFF;
            #pragma unroll
            for (int j = 0; j < 4; ++j) {
                const float d = cs[j] - acc[i][j][r];
                const int col = colbase + wc + j * 16 + l15;
                if (d < v1) { v2 = v1; i2 = i1; v1 = d; i1 = col; }
                else if (d < v2) { v2 = d; i2 = col; }
            }
            #pragma unroll
            for (int off = 8; off; off >>= 1) {
                const float ov1 = __shfl_down(v1, off, 16);
                const int oi1 = __shfl_down(i1, off, 16);
                const float ov2 = __shfl_down(v2, off, 16);
                const int oi2 = __shfl_down(i2, off, 16);
                const bool aF = (v1 < ov1) || (v1 == ov1 && i1 < oi1);
                const float w1 = aF ? v1 : ov1;   const int wi1 = aF ? i1 : oi1;
                const float lv = aF ? ov1 : v1;   const int li = aF ? oi1 : i1;   // loser's best
                const float ws2 = aF ? v2 : ov2;  const int wsi = aF ? i2 : oi2;  // winner's 2nd
                const bool c2 = (lv < ws2) || (lv == ws2 && li < wsi);
                v1 = w1; i1 = wi1;
                v2 = c2 ? lv : ws2; i2 = c2 ? li : wsi;
            }
            if (l15 == 0) {
                const int grow = rowbase + wr + i * 16 + quad * 4 + r;
                table[(size_t)grow * 64 + hb] =
                    make_float4(v1, __int_as_float(i1), v2, __int_as_float(i2));
            }
        }
    }
}

// ---------------------------------------------------------------------------
// Re-rank + gather + loss. One wave per row.
// Min over the 64 stored half-bests; if a single candidate <= min+EPS it is
// the exact argmin; else fp32 exact dist (0.5*csq - dot) for each candidate.
// ---------------------------------------------------------------------------
__global__ __launch_bounds__(256) void rerank_gather_loss_kernel(
        const float* __restrict__ x,
        const float* __restrict__ codes,
        const float* __restrict__ csq,
        const float4* __restrict__ table,
        float* __restrict__ outq,
        float* __restrict__ out_idx_f,
        float* __restrict__ partials) {
    __shared__ float red[4];
    const int t = threadIdx.x;
    const int wave = t >> 6;
    const int lane = t & 63;
    const int row = blockIdx.x * 4 + wave;

    const float4 e = table[(size_t)row * 64 + lane];
    const float v1 = e.x;  const int i1 = __float_as_int(e.y);
    const float v2 = e.z;  const int i2 = __float_as_int(e.w);

    // wave argmin over the 64 half-bests (lowest idx on ties)
    float m = v1; int mi = i1;
    #pragma unroll
    for (int off = 32; off; off >>= 1) {
        const float ov = __shfl_down(m, off, 64);
        const int oi = __shfl_down(mi, off, 64);
        if (ov < m || (ov == m && oi < mi)) { m = ov; mi = oi; }
    }
    m = __shfl(m, 0, 64);
    mi = __shfl(mi, 0, 64);

    const float thr = m + EPS;
    const unsigned long long b1 = __ballot(v1 <= thr);
    const unsigned long long b2 = __ballot(v2 <= thr);

    // x row: 8 floats/lane
    const float4* xp = (const float4*)(x + (size_t)row * D_SZ);
    const float4 x0 = xp[lane];
    const float4 x1 = xp[lane + 64];

    int fin = mi;
    if (__popcll(b1) + __popcll(b2) > 1) {
        float bv = 3.4e38f; int bi = 0x7FFFFFFF;
        #pragma unroll
        for (int pass = 0; pass < 2; ++pass) {
            unsigned long long bb = pass ? b2 : b1;
            while (bb) {
                const int src = __ffsll((unsigned long long)bb) - 1;
                bb &= bb - 1;
                const int ci = __shfl(pass ? i2 : i1, src, 64);
                const float4* cp = (const float4*)(codes + (size_t)ci * D_SZ);
                const float4 c0 = cp[lane];
                const float4 c1 = cp[lane + 64];
                float s = 0.0f;
                s = fmaf(x0.x, c0.x, s); s = fmaf(x0.y, c0.y, s);
                s = fmaf(x0.z, c0.z, s); s = fmaf(x0.w, c0.w, s);
                s = fmaf(x1.x, c1.x, s); s = fmaf(x1.y, c1.y, s);
                s = fmaf(x1.z, c1.z, s); s = fmaf(x1.w, c1.w, s);
                #pragma unroll
                for (int off = 32; off; off >>= 1) s += __shfl_xor(s, off, 64);
                const float d = fmaf(0.5f, csq[ci], -s);   // 0.5*csq - dot
                if (d < bv || (d == bv && ci < bi)) { bv = d; bi = ci; }
            }
        }
        fin = bi;
    }

    // gather + loss
    const float4* qp = (const float4*)(codes + (size_t)fin * D_SZ);
    float4* op = (float4*)(outq + (size_t)row * D_SZ);
    const float4 q0 = qp[lane];
    const float4 q1 = qp[lane + 64];
    op[lane] = q0;
    op[lane + 64] = q1;
    float s = 0.0f;
    {
        const float d0 = x0.x - q0.x, d1 = x0.y - q0.y, d2 = x0.z - q0.z, d3 = x0.w - q0.w;
        const float d4 = x1.x - q1.x, d5 = x1.y - q1.y, d6 = x1.z - q1.z, d7 = x1.w - q1.w;
        s = d0 * d0 + d1 * d1 + d2 * d2 + d3 * d3 + d4 * d4 + d5 * d5 + d6 * d6 + d7 * d7;
    }
    #pragma unroll
    for (int off = 32; off; off >>= 1) s += __shfl_down(s, off, 64);
    if (lane == 0) {
        red[wave] = s;
        out_idx_f[row] = (float)fin;
    }
    __syncthreads();
    if (t == 0) partials[blockIdx.x] = red[0] + red[1] + red[2] + red[3];
}

// ---------------------------------------------------------------------------
// Loss: sum 4096 block partials -> loss_slot. One block.
// ---------------------------------------------------------------------------
__global__ __launch_bounds__(256) void loss_reduce_kernel(const float* __restrict__ partials,
                                                          float* __restrict__ loss_slot) {
    __shared__ float red[4];
    const int t = threadIdx.x;
    const int wave = t >> 6;
    const int lane = t & 63;
    float s = 0.0f;
    #pragma unroll
    for (int i = 0; i < (B_SZ / 4) / 256; ++i) s += partials[i * 256 + t];
    #pragma unroll
    for (int off = 32; off; off >>= 1) s += __shfl_down(s, off, 64);
    if (lane == 0) red[wave] = s;
    __syncthreads();
    if (t == 0)
        *loss_slot = (red[0] + red[1] + red[2] + red[3]) * (1.25f / (float)B_SZ);
}

// ---------------------------------------------------------------------------
extern "C" void kernel_launch(void* const* d_in, const int* in_sizes, int n_in,
                              void* d_out, int out_size, void* d_ws, size_t ws_size,
                              hipStream_t stream) {
    const float* x = (const float*)d_in[0];
    const float* codes = (const float*)d_in[1];  // (1, C, D) contiguous

    float* outq = (float*)d_out;                       // [B*D]
    float* out_idx_f = outq + (size_t)B_SZ * D_SZ;     // [B]
    float* loss_slot = out_idx_f + B_SZ;               // [1]

    // workspace: xhi 16M | chi 4M | csq 16K | table 16M | partials 16K
    unsigned short* xhi = (unsigned short*)d_ws;
    unsigned short* chi = xhi + (size_t)B_SZ * D_SZ;
    float* csq = (float*)(chi + (size_t)C_SZ * D_SZ);
    float4* table = (float4*)(csq + C_SZ);
    float* partials = (float*)(table + (size_t)B_SZ * 64);

    convert_x_kernel<<<(B_SZ * D_SZ) / 4 / 256, 256, 0, stream>>>(x, xhi);
    convert_c_csq_kernel<<<C_SZ / 4, 256, 0, stream>>>(codes, chi, csq);
    gemm_argmin_kernel<<<dim3(C_SZ / 128, B_SZ / 128), 256, 0, stream>>>(xhi, chi, csq, table);
    rerank_gather_loss_kernel<<<B_SZ / 4, 256, 0, stream>>>(x, codes, csq, table, outq, out_idx_f, partials);
    loss_reduce_kernel<<<1, 256, 0, stream>>>(partials, loss_slot);
}

// Round 5
// 217.459 us; speedup vs baseline: 11.1898x; 1.1118x over previous
//
#include <hip/hip_runtime.h>

// Problem constants.
#define B_SZ 16384
#define C_SZ 4096
#define D_SZ 512

// Re-rank threshold in "dist units" (raw_l2/2). bf16 hi*hi dot error sigma
// ~= 0.07 in these units; 1.0 ~= 14 sigma. Packed-key quantization (~0.03)
// is absorbed by this margin.
#define EPS 1.0f

typedef __attribute__((ext_vector_type(8))) short short8;   // 8 bf16 = 4 VGPRs
typedef __attribute__((ext_vector_type(4))) float floatx4;  // MFMA acc

// ---- helpers ---------------------------------------------------------------
__device__ inline unsigned short f2bf(float f) {
    unsigned u = __float_as_uint(f);
    unsigned r = u + 0x7FFFu + ((u >> 16) & 1u);   // round-to-nearest-even
    return (unsigned short)(r >> 16);
}
__device__ inline void gload16(const void* g, void* l) {
    // async global->LDS, 16B/lane; LDS dest = wave-uniform base + lane*16
    __builtin_amdgcn_global_load_lds(
        (const __attribute__((address_space(1))) void*)g,
        (__attribute__((address_space(3))) void*)l, 16, 0, 0);
}
// total-order float -> u32 (ascending)
__device__ inline unsigned orderf(float f) {
    const unsigned u = __float_as_uint(f);
    return (u & 0x80000000u) ? ~u : (u | 0x80000000u);
}
// decode packed key (low 12 bits = col) back to (quantized-down) float value
__device__ inline float unorderk(unsigned k) {
    const unsigned km = k & 0xFFFFF000u;
    const unsigned u = (km & 0x80000000u) ? (km ^ 0x80000000u) : ~km;
    return __uint_as_float(u);
}

// ---------------------------------------------------------------------------
// Prep (fused): x -> bf16 hi plane; codes -> bf16 hi plane + c_sq (fp32).
// Blocks [0, 8192): x elements. Blocks [8192, 9216): one wave per code row.
// ---------------------------------------------------------------------------
__global__ __launch_bounds__(256) void convert_kernel(const float* __restrict__ x,
                                                      const float* __restrict__ codes,
                                                      unsigned short* __restrict__ xhi,
                                                      unsigned short* __restrict__ chi,
                                                      float* __restrict__ csq) {
    const int XB = (B_SZ * D_SZ) / 4 / 256;   // 8192
    if (blockIdx.x < XB) {
        const int tid = blockIdx.x * 256 + threadIdx.x;
        const float4 v = ((const float4*)x)[tid];
        ((ushort4*)xhi)[tid] = make_ushort4(f2bf(v.x), f2bf(v.y), f2bf(v.z), f2bf(v.w));
    } else {
        const int t = threadIdx.x;
        const int wave = t >> 6;
        const int lane = t & 63;
        const int code = (blockIdx.x - XB) * 4 + wave;
        const float4* cp = (const float4*)(codes + (size_t)code * D_SZ);
        float s = 0.0f;
        #pragma unroll
        for (int u = 0; u < 2; ++u) {
            const float4 v = cp[lane + 64 * u];
            ((ushort4*)chi)[(size_t)code * (D_SZ / 4) + lane + 64 * u] =
                make_ushort4(f2bf(v.x), f2bf(v.y), f2bf(v.z), f2bf(v.w));
            s = fmaf(v.x, v.x, s); s = fmaf(v.y, v.y, s);
            s = fmaf(v.z, v.z, s); s = fmaf(v.w, v.w, s);
        }
        #pragma unroll
        for (int off = 32; off; off >>= 1) s += __shfl_down(s, off, 64);
        if (lane == 0) csq[code] = s;
    }
}

// ---------------------------------------------------------------------------
// Main: hi*hi bf16 MFMA GEMM, 128x128 tile, BK=64 (8 kt iterations), XOR-
// swizzled LDS (16B chunk' = chunk ^ (row&7)) so 128B-stride rows don't bank-
// conflict; swizzle applied on the GLOBAL source address so global_load_lds's
// fixed lane->LDS mapping stays contiguous. Epilogue: top-2 per (row, 64-col
// half) via packed u32 keys (ordered-float | col), u32 shuffle merge, one
// uint2 store per entry, NO atomics.
// ---------------------------------------------------------------------------
__global__ __launch_bounds__(256) void gemm_argmin_kernel(
        const unsigned short* __restrict__ xhi,
        const unsigned short* __restrict__ chi,
        const float* __restrict__ csq,
        uint2* __restrict__ table) {
    __shared__ unsigned short sA[128][64];   // 16 KB
    __shared__ unsigned short sB[128][64];   // 16 KB

    const int t = threadIdx.x;
    const int wave = t >> 6;
    const int lane = t & 63;
    const int quad = lane >> 4;
    const int l15 = lane & 15;

    const int rowbase = blockIdx.y * 128;   // x rows
    const int colbase = blockIdx.x * 128;   // code cols
    const int wr = (wave >> 1) * 64;
    const int wc = (wave & 1) * 64;

    // staging: wave -> 64 rows of one tile; 8 gload16/kt, 8 rows per inst
    const unsigned short* gsrc;
    unsigned short(*ltile)[64];
    int rowoff;
    if (wave == 0)      { gsrc = xhi + (size_t)rowbase * D_SZ; ltile = sA; rowoff = 0; }
    else if (wave == 1) { gsrc = xhi + (size_t)rowbase * D_SZ; ltile = sA; rowoff = 64; }
    else if (wave == 2) { gsrc = chi + (size_t)colbase * D_SZ; ltile = sB; rowoff = 0; }
    else                { gsrc = chi + (size_t)colbase * D_SZ; ltile = sB; rowoff = 64; }
    const int lrow = lane >> 3;                       // 0..7 within 8-row group
    const int lchunk = (lane & 7) ^ (lrow & 7);       // swizzled 16B-chunk source
    const unsigned short* gbase = gsrc + (size_t)(rowoff + lrow) * D_SZ + lchunk * 8;

    floatx4 acc[4][4];
    #pragma unroll
    for (int i = 0; i < 4; ++i)
        #pragma unroll
        for (int j = 0; j < 4; ++j) acc[i][j] = (floatx4)0.0f;

    for (int kt = 0; kt < D_SZ / 64; ++kt) {
        const unsigned short* g = gbase + kt * 64;
        #pragma unroll
        for (int inst = 0; inst < 8; ++inst)
            gload16(g + (size_t)(inst * 8) * D_SZ, &ltile[rowoff + inst * 8][0]);
        __syncthreads();

        #pragma unroll
        for (int ksub = 0; ksub < 2; ++ksub) {
            // fragment row&7 == l15&7 (wr, wc, i*16 are multiples of 8)
            const int cc = ((ksub * 4 + quad) ^ (l15 & 7)) * 8;
            short8 a[4], b[4];
            #pragma unroll
            for (int i = 0; i < 4; ++i) {
                a[i] = *(const short8*)&sA[wr + i * 16 + l15][cc];
                b[i] = *(const short8*)&sB[wc + i * 16 + l15][cc];
            }
            #pragma unroll
            for (int i = 0; i < 4; ++i)
                #pragma unroll
                for (int j = 0; j < 4; ++j)
                    acc[i][j] = __builtin_amdgcn_mfma_f32_16x16x32_bf16(a[i], b[j], acc[i][j], 0, 0, 0);
        }
        __syncthreads();
    }

    // ---- epilogue: packed-key top-2 per (row, this wave's 64 cols)
    float cs[4];
    #pragma unroll
    for (int j = 0; j < 4; ++j)
        cs[j] = 0.5f * csq[colbase + wc + j * 16 + l15];

    const int hb = blockIdx.x * 2 + (wave & 1);   // 64-col half index, 0..63

    #pragma unroll
    for (int i = 0; i < 4; ++i) {
        #pragma unroll
        for (int r = 0; r < 4; ++r) {
            unsigned k1 = 0xFFFFFFFFu, k2 = 0xFFFFFFFFu;
            #pragma unroll
            for (int j = 0; j < 4; ++j) {
                const float d = cs[j] - acc[i][j][r];
                const unsigned key = (orderf(d) & 0xFFFFF000u)
                                   | (unsigned)(colbase + wc + j * 16 + l15);
                if (key < k1) { k2 = k1; k1 = key; }
                else if (key < k2) { k2 = key; }
            }
            #pragma unroll
            for (int off = 8; off; off >>= 1) {
                const unsigned ok1 = (unsigned)__shfl_down((int)k1, off, 16);
                const unsigned ok2 = (unsigned)__shfl_down((int)k2, off, 16);
                const unsigned lo = min(k1, ok1);
                const unsigned hi = max(k1, ok1);
                const unsigned w2 = (k1 < ok1) ? k2 : ok2;
                k1 = lo;
                k2 = min(hi, w2);
            }
            if (l15 == 0) {
                const int grow = rowbase + wr + i * 16 + quad * 4 + r;
                table[(size_t)grow * 64 + hb] = make_uint2(k1, k2);
            }
        }
    }
}

// ---------------------------------------------------------------------------
// Re-rank + gather + loss. One wave per row. Decode packed keys; if a single
// candidate <= min+EPS it is the exact argmin; else exact fp32 re-rank.
// ---------------------------------------------------------------------------
__global__ __launch_bounds__(256) void rerank_gather_loss_kernel(
        const float* __restrict__ x,
        const float* __restrict__ codes,
        const float* __restrict__ csq,
        const uint2* __restrict__ table,
        float* __restrict__ outq,
        float* __restrict__ out_idx_f,
        float* __restrict__ partials) {
    __shared__ float red[4];
    const int t = threadIdx.x;
    const int wave = t >> 6;
    const int lane = t & 63;
    const int row = blockIdx.x * 4 + wave;

    const uint2 e = table[(size_t)row * 64 + lane];
    const unsigned k1 = e.x, k2 = e.y;

    // wave min over the 64 half-best keys (ties -> lowest col, built into key)
    unsigned mk = k1;
    #pragma unroll
    for (int off = 32; off; off >>= 1)
        mk = min(mk, (unsigned)__shfl_xor((int)mk, off, 64));

    const float thr = unorderk(mk) + EPS;
    const unsigned long long b1 = __ballot(unorderk(k1) <= thr);
    const unsigned long long b2 = __ballot(unorderk(k2) <= thr);

    // x row: 8 floats/lane
    const float4* xp = (const float4*)(x + (size_t)row * D_SZ);
    const float4 x0 = xp[lane];
    const float4 x1 = xp[lane + 64];

    int fin = (int)(mk & 0xFFFu);
    if (__popcll(b1) + __popcll(b2) > 1) {
        float bv = 3.4e38f; int bi = 0x7FFFFFFF;
        #pragma unroll
        for (int pass = 0; pass < 2; ++pass) {
            unsigned long long bb = pass ? b2 : b1;
            const int myc = (int)((pass ? k2 : k1) & 0xFFFu);
            while (bb) {
                const int src = __ffsll((unsigned long long)bb) - 1;
                bb &= bb - 1;
                const int ci = __shfl(myc, src, 64);
                const float4* cp = (const float4*)(codes + (size_t)ci * D_SZ);
                const float4 c0 = cp[lane];
                const float4 c1 = cp[lane + 64];
                float s = 0.0f;
                s = fmaf(x0.x, c0.x, s); s = fmaf(x0.y, c0.y, s);
                s = fmaf(x0.z, c0.z, s); s = fmaf(x0.w, c0.w, s);
                s = fmaf(x1.x, c1.x, s); s = fmaf(x1.y, c1.y, s);
                s = fmaf(x1.z, c1.z, s); s = fmaf(x1.w, c1.w, s);
                #pragma unroll
                for (int off = 32; off; off >>= 1) s += __shfl_xor(s, off, 64);
                const float d = fmaf(0.5f, csq[ci], -s);   // 0.5*csq - dot
                if (d < bv || (d == bv && ci < bi)) { bv = d; bi = ci; }
            }
        }
        fin = bi;
    }

    // gather + loss
    const float4* qp = (const float4*)(codes + (size_t)fin * D_SZ);
    float4* op = (float4*)(outq + (size_t)row * D_SZ);
    const float4 q0 = qp[lane];
    const float4 q1 = qp[lane + 64];
    op[lane] = q0;
    op[lane + 64] = q1;
    float s = 0.0f;
    {
        const float d0 = x0.x - q0.x, d1 = x0.y - q0.y, d2 = x0.z - q0.z, d3 = x0.w - q0.w;
        const float d4 = x1.x - q1.x, d5 = x1.y - q1.y, d6 = x1.z - q1.z, d7 = x1.w - q1.w;
        s = d0 * d0 + d1 * d1 + d2 * d2 + d3 * d3 + d4 * d4 + d5 * d5 + d6 * d6 + d7 * d7;
    }
    #pragma unroll
    for (int off = 32; off; off >>= 1) s += __shfl_down(s, off, 64);
    if (lane == 0) {
        red[wave] = s;
        out_idx_f[row] = (float)fin;
    }
    __syncthreads();
    if (t == 0) partials[blockIdx.x] = red[0] + red[1] + red[2] + red[3];
}

// ---------------------------------------------------------------------------
// Loss: sum 4096 block partials -> loss_slot. One block.
// ---------------------------------------------------------------------------
__global__ __launch_bounds__(256) void loss_reduce_kernel(const float* __restrict__ partials,
                                                          float* __restrict__ loss_slot) {
    __shared__ float red[4];
    const int t = threadIdx.x;
    const int wave = t >> 6;
    const int lane = t & 63;
    float s = 0.0f;
    #pragma unroll
    for (int i = 0; i < (B_SZ / 4) / 256; ++i) s += partials[i * 256 + t];
    #pragma unroll
    for (int off = 32; off; off >>= 1) s += __shfl_down(s, off, 64);
    if (lane == 0) red[wave] = s;
    __syncthreads();
    if (t == 0)
        *loss_slot = (red[0] + red[1] + red[2] + red[3]) * (1.25f / (float)B_SZ);
}

// ---------------------------------------------------------------------------
extern "C" void kernel_launch(void* const* d_in, const int* in_sizes, int n_in,
                              void* d_out, int out_size, void* d_ws, size_t ws_size,
                              hipStream_t stream) {
    const float* x = (const float*)d_in[0];
    const float* codes = (const float*)d_in[1];  // (1, C, D) contiguous

    float* outq = (float*)d_out;                       // [B*D]
    float* out_idx_f = outq + (size_t)B_SZ * D_SZ;     // [B]
    float* loss_slot = out_idx_f + B_SZ;               // [1]

    // workspace: xhi 16M | chi 4M | csq 16K | table 8M (uint2) | partials 16K
    unsigned short* xhi = (unsigned short*)d_ws;
    unsigned short* chi = xhi + (size_t)B_SZ * D_SZ;
    float* csq = (float*)(chi + (size_t)C_SZ * D_SZ);
    uint2* table = (uint2*)(csq + C_SZ);
    float* partials = (float*)(table + (size_t)B_SZ * 64);

    const int XB = (B_SZ * D_SZ) / 4 / 256;           // 8192
    const int CB = C_SZ / 4;                          // 1024
    convert_kernel<<<XB + CB, 256, 0, stream>>>(x, codes, xhi, chi, csq);
    gemm_argmin_kernel<<<dim3(C_SZ / 128, B_SZ / 128), 256, 0, stream>>>(xhi, chi, csq, table);
    rerank_gather_loss_kernel<<<B_SZ / 4, 256, 0, stream>>>(x, codes, csq, table, outq, out_idx_f, partials);
    loss_reduce_kernel<<<1, 256, 0, stream>>>(partials, loss_slot);
}

// Round 6
// 192.967 us; speedup vs baseline: 12.6100x; 1.1269x over previous
//
#include <hip/hip_runtime.h>

// Problem constants.
#define B_SZ 16384
#define C_SZ 4096
#define D_SZ 512

// Re-rank threshold in "dist units" (raw_l2/2). bf16 hi*hi dot error sigma
// ~= 0.07; max approx err ~0.4; key quantization (6 bits masked at value
// ~2^10) ~0.008. 2*0.4 + 0.02 < 1.0 = EPS.
#define EPS 1.0f
// Bias making dist' = BIAS + 0.5*csq - dot strictly positive (needs
// BIAS > 0.5*xsq; xsq ~ chi2(512) <= ~700 at 14 sigma).
#define DBIAS 1024.0f

typedef __attribute__((ext_vector_type(8))) short short8;   // 8 bf16 = 4 VGPRs
typedef __attribute__((ext_vector_type(4))) float floatx4;  // MFMA acc

// ---- helpers ---------------------------------------------------------------
__device__ inline unsigned short f2bf(float f) {
    unsigned u = __float_as_uint(f);
    unsigned r = u + 0x7FFFu + ((u >> 16) & 1u);   // round-to-nearest-even
    return (unsigned short)(r >> 16);
}
__device__ inline void gload16(const void* g, void* l) {
    // async global->LDS, 16B/lane; LDS dest = wave-uniform base + lane*16
    __builtin_amdgcn_global_load_lds(
        (const __attribute__((address_space(1))) void*)g,
        (__attribute__((address_space(3))) void*)l, 16, 0, 0);
}

// ---------------------------------------------------------------------------
// Prep (fused): x -> bf16 hi plane; codes -> bf16 hi plane + c_sq (fp32).
// Blocks [0, 8192): x elements. Blocks [8192, 9216): one wave per code row.
// ---------------------------------------------------------------------------
__global__ __launch_bounds__(256) void convert_kernel(const float* __restrict__ x,
                                                      const float* __restrict__ codes,
                                                      unsigned short* __restrict__ xhi,
                                                      unsigned short* __restrict__ chi,
                                                      float* __restrict__ csq) {
    const int XB = (B_SZ * D_SZ) / 4 / 256;   // 8192
    if (blockIdx.x < XB) {
        const int tid = blockIdx.x * 256 + threadIdx.x;
        const float4 v = ((const float4*)x)[tid];
        ((ushort4*)xhi)[tid] = make_ushort4(f2bf(v.x), f2bf(v.y), f2bf(v.z), f2bf(v.w));
    } else {
        const int t = threadIdx.x;
        const int wave = t >> 6;
        const int lane = t & 63;
        const int code = (blockIdx.x - XB) * 4 + wave;
        const float4* cp = (const float4*)(codes + (size_t)code * D_SZ);
        float s = 0.0f;
        #pragma unroll
        for (int u = 0; u < 2; ++u) {
            const float4 v = cp[lane + 64 * u];
            ((ushort4*)chi)[(size_t)code * (D_SZ / 4) + lane + 64 * u] =
                make_ushort4(f2bf(v.x), f2bf(v.y), f2bf(v.z), f2bf(v.w));
            s = fmaf(v.x, v.x, s); s = fmaf(v.y, v.y, s);
            s = fmaf(v.z, v.z, s); s = fmaf(v.w, v.w, s);
        }
        #pragma unroll
        for (int off = 32; off; off >>= 1) s += __shfl_down(s, off, 64);
        if (lane == 0) csq[code] = s;
    }
}

// ---------------------------------------------------------------------------
// Main: hi*hi bf16 MFMA GEMM, 128x128 block tile, 8 waves (512 thr), wave =
// 32 rows x 64 cols (acc = 8 tiles = 32 AGPR -> 4 waves/SIMD occupancy).
// BK=64, XOR-swizzled LDS (16B chunk' = chunk ^ (row&7)), zero conflicts.
// Epilogue: dist' = (DBIAS + 0.5*csq) - dot > 0 -> raw float bits are
// order-monotone; key = (bits & ~63) | (col low 6 bits). Top-2 of 4 via
// min/max network, 4-step u32 16-lane merge, one uint2 store per
// (row, 64-col half). NO atomics.
// ---------------------------------------------------------------------------
__global__ __launch_bounds__(512, 4) void gemm_argmin_kernel(
        const unsigned short* __restrict__ xhi,
        const unsigned short* __restrict__ chi,
        const float* __restrict__ csq,
        uint2* __restrict__ table) {
    __shared__ unsigned short sA[128][64];   // 16 KB
    __shared__ unsigned short sB[128][64];   // 16 KB

    const int t = threadIdx.x;
    const int wave = t >> 6;     // 0..7
    const int lane = t & 63;
    const int quad = lane >> 4;
    const int l15 = lane & 15;

    const int rowbase = blockIdx.y * 128;   // x rows
    const int colbase = blockIdx.x * 128;   // code cols
    const int wr = (wave >> 1) * 32;        // wave's 32-row strip
    const int wc = (wave & 1) * 64;         // wave's 64-col half

    // staging: waves 0-3 stage A rows w*32..+32; waves 4-7 stage B similarly.
    // 4 gload16 per wave per kt, 8 rows per inst.
    const unsigned short* gsrc;
    unsigned short(*ltile)[64];
    int rowoff;
    if (wave < 4) { gsrc = xhi + (size_t)rowbase * D_SZ; ltile = sA; rowoff = wave * 32; }
    else          { gsrc = chi + (size_t)colbase * D_SZ; ltile = sB; rowoff = (wave - 4) * 32; }
    const int lrow = lane >> 3;                       // 0..7 within 8-row group
    const int lchunk = (lane & 7) ^ (lrow & 7);       // swizzled 16B-chunk source
    const unsigned short* gbase = gsrc + (size_t)(rowoff + lrow) * D_SZ + lchunk * 8;

    // epilogue csq terms, loaded up front (L2-resident)
    float cs2[4];
    #pragma unroll
    for (int j = 0; j < 4; ++j)
        cs2[j] = fmaf(0.5f, csq[colbase + wc + j * 16 + l15], DBIAS);

    floatx4 acc[2][4];
    #pragma unroll
    for (int i = 0; i < 2; ++i)
        #pragma unroll
        for (int j = 0; j < 4; ++j) acc[i][j] = (floatx4)0.0f;

    for (int kt = 0; kt < D_SZ / 64; ++kt) {
        const unsigned short* g = gbase + kt * 64;
        #pragma unroll
        for (int inst = 0; inst < 4; ++inst)
            gload16(g + (size_t)(inst * 8) * D_SZ, &ltile[rowoff + inst * 8][0]);
        __syncthreads();

        #pragma unroll
        for (int ksub = 0; ksub < 2; ++ksub) {
            const int cc = ((ksub * 4 + quad) ^ (l15 & 7)) * 8;
            short8 a[2], b[4];
            #pragma unroll
            for (int i = 0; i < 2; ++i)
                a[i] = *(const short8*)&sA[wr + i * 16 + l15][cc];
            #pragma unroll
            for (int j = 0; j < 4; ++j)
                b[j] = *(const short8*)&sB[wc + j * 16 + l15][cc];
            #pragma unroll
            for (int i = 0; i < 2; ++i)
                #pragma unroll
                for (int j = 0; j < 4; ++j)
                    acc[i][j] = __builtin_amdgcn_mfma_f32_16x16x32_bf16(a[i], b[j], acc[i][j], 0, 0, 0);
        }
        __syncthreads();
    }

    // ---- epilogue: packed-key top-2 per (row, this wave's 64-col half)
    const int hb = blockIdx.x * 2 + (wave & 1);   // 64-col half index, 0..63

    #pragma unroll
    for (int i = 0; i < 2; ++i) {
        #pragma unroll
        for (int r = 0; r < 4; ++r) {
            unsigned k[4];
            #pragma unroll
            for (int j = 0; j < 4; ++j) {
                const float d = cs2[j] - acc[i][j][r];   // > 0 by DBIAS
                k[j] = (__float_as_uint(d) & 0xFFFFFFC0u) | (unsigned)(j * 16 + l15);
            }
            // top-2-of-4 min/max network
            const unsigned lo1 = min(k[0], k[1]), hi1 = max(k[0], k[1]);
            const unsigned lo2 = min(k[2], k[3]), hi2 = max(k[2], k[3]);
            unsigned k1 = min(lo1, lo2);
            unsigned k2 = min(max(lo1, lo2), min(hi1, hi2));
            // 16-lane top-2 merge
            #pragma unroll
            for (int off = 8; off; off >>= 1) {
                const unsigned ok1 = (unsigned)__shfl_down((int)k1, off, 16);
                const unsigned ok2 = (unsigned)__shfl_down((int)k2, off, 16);
                const unsigned hi = max(k1, ok1);
                const unsigned w2 = (k1 < ok1) ? k2 : ok2;
                k1 = min(k1, ok1);
                k2 = min(hi, w2);
            }
            if (l15 == 0) {
                const int grow = rowbase + wr + i * 16 + quad * 4 + r;
                table[(size_t)grow * 64 + hb] = make_uint2(k1, k2);
            }
        }
    }
}

// ---------------------------------------------------------------------------
// Re-rank + gather + loss. One wave per row. Keys are positive-float bits;
// col = 64*lane + (key & 63). If a single candidate <= min+EPS it is the
// exact argmin; else exact fp32 re-rank (lowest index on ties).
// ---------------------------------------------------------------------------
__global__ __launch_bounds__(256) void rerank_gather_loss_kernel(
        const float* __restrict__ x,
        const float* __restrict__ codes,
        const float* __restrict__ csq,
        const uint2* __restrict__ table,
        float* __restrict__ outq,
        float* __restrict__ out_idx_f,
        float* __restrict__ partials) {
    __shared__ float red[4];
    const int t = threadIdx.x;
    const int wave = t >> 6;
    const int lane = t & 63;
    const int row = blockIdx.x * 4 + wave;

    const uint2 e = table[(size_t)row * 64 + lane];
    const unsigned k1 = e.x, k2 = e.y;

    // wave min over the 64 half-best keys
    unsigned mk = k1;
    #pragma unroll
    for (int off = 32; off; off >>= 1)
        mk = min(mk, (unsigned)__shfl_xor((int)mk, off, 64));

    const float thr = __uint_as_float(mk & 0xFFFFFFC0u) + EPS;
    const float v1 = __uint_as_float(k1 & 0xFFFFFFC0u);
    const float v2 = __uint_as_float(k2 & 0xFFFFFFC0u);
    const unsigned long long b1 = __ballot(v1 <= thr);
    const unsigned long long b2 = __ballot(v2 <= thr);

    // default argmin: lowest lane (= lowest half = lowest col) holding mk
    const unsigned long long bm = __ballot(k1 == mk);
    const int mhb = __ffsll(bm) - 1;
    int fin = mhb * 64 + (int)(mk & 63u);

    // x row: 8 floats/lane
    const float4* xp = (const float4*)(x + (size_t)row * D_SZ);
    const float4 x0 = xp[lane];
    const float4 x1 = xp[lane + 64];

    if (__popcll(b1) + __popcll(b2) > 1) {
        const int c1 = lane * 64 + (int)(k1 & 63u);
        const int c2 = lane * 64 + (int)(k2 & 63u);
        float bv = 3.4e38f; int bi = 0x7FFFFFFF;
        #pragma unroll
        for (int pass = 0; pass < 2; ++pass) {
            unsigned long long bb = pass ? b2 : b1;
            const int myc = pass ? c2 : c1;
            while (bb) {
                const int src = __ffsll((unsigned long long)bb) - 1;
                bb &= bb - 1;
                const int ci = __shfl(myc, src, 64);
                const float4* cp = (const float4*)(codes + (size_t)ci * D_SZ);
                const float4 c0 = cp[lane];
                const float4 c1v = cp[lane + 64];
                float s = 0.0f;
                s = fmaf(x0.x, c0.x, s); s = fmaf(x0.y, c0.y, s);
                s = fmaf(x0.z, c0.z, s); s = fmaf(x0.w, c0.w, s);
                s = fmaf(x1.x, c1v.x, s); s = fmaf(x1.y, c1v.y, s);
                s = fmaf(x1.z, c1v.z, s); s = fmaf(x1.w, c1v.w, s);
                #pragma unroll
                for (int off = 32; off; off >>= 1) s += __shfl_xor(s, off, 64);
                const float d = fmaf(0.5f, csq[ci], -s);   // 0.5*csq - dot (exact fp32)
                if (d < bv || (d == bv && ci < bi)) { bv = d; bi = ci; }
            }
        }
        fin = bi;
    }

    // gather + loss
    const float4* qp = (const float4*)(codes + (size_t)fin * D_SZ);
    float4* op = (float4*)(outq + (size_t)row * D_SZ);
    const float4 q0 = qp[lane];
    const float4 q1 = qp[lane + 64];
    op[lane] = q0;
    op[lane + 64] = q1;
    float s = 0.0f;
    {
        const float d0 = x0.x - q0.x, d1 = x0.y - q0.y, d2 = x0.z - q0.z, d3 = x0.w - q0.w;
        const float d4 = x1.x - q1.x, d5 = x1.y - q1.y, d6 = x1.z - q1.z, d7 = x1.w - q1.w;
        s = d0 * d0 + d1 * d1 + d2 * d2 + d3 * d3 + d4 * d4 + d5 * d5 + d6 * d6 + d7 * d7;
    }
    #pragma unroll
    for (int off = 32; off; off >>= 1) s += __shfl_down(s, off, 64);
    if (lane == 0) {
        red[wave] = s;
        out_idx_f[row] = (float)fin;
    }
    __syncthreads();
    if (t == 0) partials[blockIdx.x] = red[0] + red[1] + red[2] + red[3];
}

// ---------------------------------------------------------------------------
// Loss: sum 4096 block partials -> loss_slot. One block.
// ---------------------------------------------------------------------------
__global__ __launch_bounds__(256) void loss_reduce_kernel(const float* __restrict__ partials,
                                                          float* __restrict__ loss_slot) {
    __shared__ float red[4];
    const int t = threadIdx.x;
    const int wave = t >> 6;
    const int lane = t & 63;
    float s = 0.0f;
    #pragma unroll
    for (int i = 0; i < (B_SZ / 4) / 256; ++i) s += partials[i * 256 + t];
    #pragma unroll
    for (int off = 32; off; off >>= 1) s += __shfl_down(s, off, 64);
    if (lane == 0) red[wave] = s;
    __syncthreads();
    if (t == 0)
        *loss_slot = (red[0] + red[1] + red[2] + red[3]) * (1.25f / (float)B_SZ);
}

// ---------------------------------------------------------------------------
extern "C" void kernel_launch(void* const* d_in, const int* in_sizes, int n_in,
                              void* d_out, int out_size, void* d_ws, size_t ws_size,
                              hipStream_t stream) {
    const float* x = (const float*)d_in[0];
    const float* codes = (const float*)d_in[1];  // (1, C, D) contiguous

    float* outq = (float*)d_out;                       // [B*D]
    float* out_idx_f = outq + (size_t)B_SZ * D_SZ;     // [B]
    float* loss_slot = out_idx_f + B_SZ;               // [1]

    // workspace: xhi 16M | chi 4M | csq 16K | table 8M (uint2) | partials 16K
    unsigned short* xhi = (unsigned short*)d_ws;
    unsigned short* chi = xhi + (size_t)B_SZ * D_SZ;
    float* csq = (float*)(chi + (size_t)C_SZ * D_SZ);
    uint2* table = (uint2*)(csq + C_SZ);
    float* partials = (float*)(table + (size_t)B_SZ * 64);

    const int XB = (B_SZ * D_SZ) / 4 / 256;           // 8192
    const int CB = C_SZ / 4;                          // 1024
    convert_kernel<<<XB + CB, 256, 0, stream>>>(x, codes, xhi, chi, csq);
    gemm_argmin_kernel<<<dim3(C_SZ / 128, B_SZ / 128), 512, 0, stream>>>(xhi, chi, csq, table);
    rerank_gather_loss_kernel<<<B_SZ / 4, 256, 0, stream>>>(x, codes, csq, table, outq, out_idx_f, partials);
    loss_reduce_kernel<<<1, 256, 0, stream>>>(partials, loss_slot);
}